// Round 6
// baseline (367.567 us; speedup 1.0000x reference)
//
#include <hip/hip_runtime.h>
#include <cstdint>
#include <cstddef>

// Binarized basic block on MI355X.
// |acc| <= 9*128 = 1152 < THRESH=8000 -> the per-partial-sum clip never binds
// -> both convs are exact int convolutions of sign() values. int8 implicit
// GEMM via mfma_i32_16x16x64_i8; float ops bit-exact vs numpy fp32.
//
// R15 (on R12 base; R14's RG3-merge + prep fusion REVERTED): STREAMING
// PHASE-2 EPILOGUE + per-phase kernel names.
//  R14 post-mortem: hbm_bytes 214 MB / 2.1 TB/s = 102 us ~= the whole conv
//  duration -> the kernel is L2-miss-BW-bound at the ~2 TB/s ceiling of
//  64-B-granule scattered traffic. The payer is phase-2's epilogue: xres/out
//  are channel-plane gathers (16 disjoint 64-B segments / instruction).
//  K-loop restructures (R10-R14) never moved the wall because the K-loop
//  never owned it.
//  -> epi_p2: block-staged LDS transpose. 16 passes; pass p: lanes l15==p
//     dump BN'd acc octet to sm[8][256] (8 KB); barrier; 512 threads read
//     back 16 B each -> x-read + out-write become 1-KB contiguous segments
//     (PIX%4==0 -> no b-straddle inside a v4f). Same bytes, 16x granule.
//  -> conv_p1 / conv_p2 named separately for rocprof attribution (never
//     actually seen them individually before).

typedef int      v4i __attribute__((ext_vector_type(4)));
typedef float    v4f __attribute__((ext_vector_type(4)));
typedef unsigned int v2u __attribute__((ext_vector_type(2)));

constexpr int B = 64, C = 128, H = 56, W = 56;
constexpr int HP = H + 2, WP = W + 2;      // zero-padded spatial
constexpr int PIX = H * W;                 // 3136
constexpr int M = B * H * W;               // 200704 = 784 * 256
constexpr int NTILES = M / 256;            // 784 tiles of 256 rows
constexpr int TPX = NTILES / 8;            // 98 tiles per XCD

// workspace layout (bytes)
constexpr size_t XS_BYTES = (size_t)B * HP * WP * C;   // 27,557,888
constexpr size_t XS1_OFF = 0;
constexpr size_t XS2_OFF = XS_BYTES;
constexpr size_t WF_BYTES = 18 * 8192;                 // 147,456
constexpr size_t WF1_OFF = 2 * XS_BYTES;
constexpr size_t WF2_OFF = WF1_OFF + WF_BYTES;
constexpr size_t BNP_OFF = WF2_OFF + WF_BYTES;         // 4*128 floats

// ---------------------------------------------------------------------------
// Zero only the padded halos of xs1/xs2. 256 blocks: 4 per image.
__global__ __launch_bounds__(256) void zero_halo(int8_t* __restrict__ xs1,
                                                 int8_t* __restrict__ xs2) {
    int b = blockIdx.x >> 2;
    int q = blockIdx.x & 3;
    int t = q * 256 + threadIdx.x;           // 0..1023
    size_t ib = (size_t)b * HP * WP * C;
#pragma unroll
    for (int a = 0; a < 2; ++a) {
        uint32_t* p = (uint32_t*)((a ? xs2 : xs1) + ib);
        const int ROWD = WP * C / 4;             // 1856 dwords per padded row
        for (int i = t; i < ROWD; i += 1024) {
            p[i] = 0;
            p[(HP - 1) * ROWD + i] = 0;
        }
        for (int i = t; i < 56 * 2 * 32; i += 1024) {
            int r = i >> 6;
            int side = (i >> 5) & 1;
            int j = i & 31;
            p[((r + 1) * WP + side * (WP - 1)) * (C / 4) + j] = 0;
        }
    }
}

// ---------------------------------------------------------------------------
// sign(x) -> padded NHWC int8 via LDS transpose (16 B/lane full-line stores).
__global__ __launch_bounds__(256) void prep_x(const float* __restrict__ x,
                                              int8_t* __restrict__ xs) {
    __shared__ uint32_t tl[256 * 33];
    int t = threadIdx.x;
    int m = blockIdx.x * 256 + t;
    int b_ = m / PIX, hw = m % PIX;
    const float* xp = x + (size_t)b_ * C * PIX + hw;
#pragma unroll
    for (int c4 = 0; c4 < 32; ++c4) {
        uint32_t v = 0;
#pragma unroll
        for (int j = 0; j < 4; ++j) {
            float f = __builtin_nontemporal_load(xp + (size_t)(c4 * 4 + j) * PIX);
            v |= ((uint32_t)(uint8_t)(int8_t)((f > 0.f) - (f < 0.f))) << (8 * j);
        }
        tl[t * 33 + c4] = v;
    }
    __syncthreads();
    int pl = t >> 3, co = t & 7;
#pragma unroll
    for (int pass = 0; pass < 8; ++pass) {
        int p = pass * 32 + pl;
        int mg = blockIdx.x * 256 + p;
        int b2 = mg / PIX, hw2 = mg % PIX, h2 = hw2 / W, w2 = hw2 % W;
        size_t ob = ((size_t)(b2 * HP + h2 + 1) * WP + (w2 + 1)) * C + co * 16;
        v4i val;
#pragma unroll
        for (int k = 0; k < 4; ++k) val[k] = (int)tl[p * 33 + co * 4 + k];
        *(v4i*)(xs + ob) = val;
    }
}

// ---------------------------------------------------------------------------
// Binarize weights into MFMA B-fragment order, slot = r*6 + kh*3 + s, with
// o = (lane&15)*8 + n (lane-contiguous O). BN tables exactly numpy fp32.
__global__ __launch_bounds__(256) void prep_w(
    const float* __restrict__ w1, const float* __restrict__ w2,
    const float* __restrict__ g1, const float* __restrict__ be1,
    const float* __restrict__ mu1, const float* __restrict__ va1,
    const float* __restrict__ g2, const float* __restrict__ be2,
    const float* __restrict__ mu2, const float* __restrict__ va2,
    int8_t* __restrict__ wf1, int8_t* __restrict__ wf2,
    float* __restrict__ bnp) {
    int t = blockIdx.x * 256 + threadIdx.x;
    if (t < 256) {
        int o = t & 127;
        if (t < 128) {
            float inv = g1[o] / sqrtf(va1[o] + 1e-5f);
            bnp[o]       = inv;
            bnp[128 + o] = __fsub_rn(be1[o], __fmul_rn(mu1[o], inv));
        } else {
            float inv = g2[o] / sqrtf(va2[o] + 1e-5f);
            bnp[256 + o] = inv;
            bnp[384 + o] = __fsub_rn(be2[o], __fmul_rn(mu2[o], inv));
        }
    }
    if (t >= 2 * 18 * 8 * 64) return;
    int lane = t & 63;
    int nsub = (t >> 6) & 7;
    int kh   = (t >> 9) & 1;
    int tap  = (t >> 10) % 9;
    int which = (t >> 10) / 9;
    const float* w = which ? w2 : w1;
    int8_t* wf = which ? wf2 : wf1;
    int o = (lane & 15) * 8 + nsub;
    int cbase = kh * 64 + (lane >> 4) * 16;
    int r = tap / 3, s = tap % 3;
    int slot = r * 6 + kh * 3 + s;           // (r, kh, s) step order
    int8_t frag[16];
#pragma unroll
    for (int j = 0; j < 16; ++j) {
        float f = w[((size_t)(o * C + cbase + j) * 3 + r) * 3 + s];
        frag[j] = (int8_t)((f > 0.f) - (f < 0.f));
    }
    *(v4i*)(wf + (size_t)((slot * 8 + nsub) * 64 + lane) * 16) =
        *(const v4i*)frag;
}

// ---------------------------------------------------------------------------
// K-loop only (R12's pinned ping-pong, verbatim): RG row-groups x 128 O.
template <int RG>
__device__ __forceinline__ void do_conv(
    int mwave, const int8_t* __restrict__ xs, const int8_t* wlds,
    int lane, int quad, int l15, v4i (&acc)[RG][8])
{
    int abase[RG];
#pragma unroll
    for (int rg = 0; rg < RG; ++rg) {
        int ma = mwave + rg * 16 + l15;
        int wa = ma % W; int ta = ma / W; int ha = ta % H; int ba = ta / H;
        abase[rg] = ((ba * HP + ha) * WP + wa) * C + quad * 16;
    }
    int lidx = lane << 4;

#pragma unroll
    for (int rg = 0; rg < RG; ++rg)
#pragma unroll
        for (int n = 0; n < 8; ++n) acc[rg][n] = (v4i)0;

    v4i a0[RG], a1[RG], bf0[8], bf1[8];
#pragma unroll
    for (int rg = 0; rg < RG; ++rg) a0[rg] = *(const v4i*)(xs + abase[rg]);
#pragma unroll
    for (int n = 0; n < 8; ++n)
        bf0[n] = *(const v4i*)(wlds + n * 1024 + lidx);
    __builtin_amdgcn_sched_barrier(0);

    const int8_t* wl = wlds;
    int aoffr = 0;
#pragma unroll 1
    for (int r3 = 0; r3 < 3; ++r3) {
#pragma unroll
        for (int kk = 0; kk < 6; ++kk) {
            const bool last = (r3 == 2) && (kk == 5);
            if (!last) {
                const int nkh = (kk + 1 < 6) ? ((kk + 1) / 3) : 0;
                const int ns  = (kk + 1 < 6) ? ((kk + 1) % 3) : 0;
                const int rbump = (kk + 1 < 6) ? 0 : WP * C;
                int naoff = aoffr + rbump + nkh * 64 + ns * C;
                const int8_t* lb = wl + (kk + 1) * 8192;
                if (((kk + 1) & 1) == 0) {
#pragma unroll
                    for (int rg = 0; rg < RG; ++rg)
                        a0[rg] = *(const v4i*)(xs + abase[rg] + naoff);
#pragma unroll
                    for (int n = 0; n < 8; ++n)
                        bf0[n] = *(const v4i*)(lb + n * 1024 + lidx);
                } else {
#pragma unroll
                    for (int rg = 0; rg < RG; ++rg)
                        a1[rg] = *(const v4i*)(xs + abase[rg] + naoff);
#pragma unroll
                    for (int n = 0; n < 8; ++n)
                        bf1[n] = *(const v4i*)(lb + n * 1024 + lidx);
                }
            }
            __builtin_amdgcn_sched_barrier(0);
            __builtin_amdgcn_s_setprio(1);
            if ((kk & 1) == 0) {
#pragma unroll
                for (int n = 0; n < 8; ++n)
#pragma unroll
                    for (int rg = 0; rg < RG; ++rg)
                        acc[rg][n] = __builtin_amdgcn_mfma_i32_16x16x64_i8(
                            a0[rg], bf0[n], acc[rg][n], 0, 0, 0);
            } else {
#pragma unroll
                for (int n = 0; n < 8; ++n)
#pragma unroll
                    for (int rg = 0; rg < RG; ++rg)
                        acc[rg][n] = __builtin_amdgcn_mfma_i32_16x16x64_i8(
                            a1[rg], bf1[n], acc[rg][n], 0, 0, 0);
            }
            __builtin_amdgcn_s_setprio(0);
            __builtin_amdgcn_sched_barrier(0);
        }
        aoffr += WP * C;
        wl += 6 * 8192;
    }
}

// ---------------------------------------------------------------------------
// Phase-1 epilogue (per-wave, unchanged): sign(bn(acc)) -> xs_next, full-line
// v2u stores (128-B contiguous per 16 lanes).
template <int RG>
__device__ __forceinline__ void epi_p1(
    v4i (&acc)[RG][8], int mwave, int quad, int l15,
    const float* binv, const float* btt, int8_t* __restrict__ xs_next)
{
#pragma unroll
    for (int rg = 0; rg < RG; ++rg) {
        int m0 = mwave + rg * 16 + quad * 4;
        int w0 = m0 % W; int t0 = m0 / W; int h0 = t0 % H; int b0 = t0 / H;
        int base = ((b0 * HP + h0 + 1) * WP + (w0 + 1)) * C + l15 * 8;
#pragma unroll
        for (int i = 0; i < 4; ++i) {
            uint32_t lo = 0, hi = 0;
#pragma unroll
            for (int n = 0; n < 8; ++n) {
                float y = __fadd_rn(__fmul_rn((float)acc[rg][n][i], binv[n]), btt[n]);
                uint32_t sb = (uint8_t)(int8_t)((y > 0.f) - (y < 0.f));
                if (n < 4) lo |= sb << (8 * n);
                else       hi |= sb << (8 * (n - 4));
            }
            v2u pk; pk[0] = lo; pk[1] = hi;
            *(v2u*)(xs_next + base + i * C) = pk;
        }
    }
}

// ---------------------------------------------------------------------------
// Phase-2 epilogue (block-staged, barriers): 16 passes through an 8-KB LDS
// buffer turn x-reads + out-writes into 1-KB contiguous segments.
// m0 = block's window base in m-space (window = 128*RG px, m0 % 4 == 0).
template <int RG>
__device__ __forceinline__ void epi_p2(
    v4i (&acc)[RG][8], int m0, int wv, int quad, int l15,
    const float* binv, const float* btt,
    const float* __restrict__ xres, float* __restrict__ out, float* sm)
{
    constexpr int PXB = 128 * RG;            // px in block window
    int t = wv * 64 + quad * 16 + l15;       // == threadIdx.x
#pragma unroll 1
    for (int p = 0; p < 16; ++p) {
        if (l15 == p) {
#pragma unroll
            for (int rg = 0; rg < RG; ++rg)
#pragma unroll
                for (int n = 0; n < 8; ++n) {
                    v4f v;
#pragma unroll
                    for (int i = 0; i < 4; ++i)
                        v[i] = __fadd_rn(__fmul_rn((float)acc[rg][n][i],
                                                   binv[n]), btt[n]);
                    *(v4f*)(sm + n * PXB + wv * (RG * 16) + rg * 16 + quad * 4) = v;
                }
        }
        __syncthreads();
        if (t < PXB * 2) {                   // PXB*8/4 v4f chunks
            int o_local = t / (PXB / 4);
            int px4 = (t % (PXB / 4)) * 4;
            v4f s = *(const v4f*)(sm + o_local * PXB + px4);
            int m = m0 + px4;
            int b0 = m / PIX, pp = m - b0 * PIX;   // pp%4==0, no straddle
            size_t gidx = ((size_t)(b0 * C + p * 8 + o_local)) * PIX + pp;
            v4f r = *(const v4f*)(xres + gidx);
            v4f z;
#pragma unroll
            for (int i = 0; i < 4; ++i)
                z[i] = fminf(fmaxf(__fadd_rn(s[i], r[i]), -1.f), 1.f);
            __builtin_nontemporal_store(z, (v4f*)(out + gidx));
        }
        __syncthreads();
    }
}

// ---------------------------------------------------------------------------
// Phase 1: persistent conv, R12 schedule (3 rounds + 4-block tail round).
__global__ __launch_bounds__(512, 1) void conv_p1(
    const int8_t* __restrict__ xs,
    const int8_t* __restrict__ wf,
    const float* __restrict__ bnp,
    int8_t* __restrict__ xs_next)
{
    __shared__ int8_t wlds[18 * 8192];       // 147,456 B
    int t = threadIdx.x, lane = t & 63, wv = t >> 6;
    int quad = lane >> 4, l15 = lane & 15;

    {
        const v4i* g = (const v4i*)wf;
        v4i* l = (v4i*)wlds;
        for (int i = t; i < 18 * 512; i += 512) l[i] = g[i];
    }
    float binv[8], btt[8];
    {
        int o0 = l15 * 8, o1 = 128 + l15 * 8;
#pragma unroll
        for (int n = 0; n < 8; ++n) { binv[n] = bnp[o0 + n]; btt[n] = bnp[o1 + n]; }
    }
    __syncthreads();

    int xcd = blockIdx.x & 7, local = blockIdx.x >> 3;
#pragma unroll 1
    for (int tloc = local; tloc < 96; tloc += 32) {
        int mw = (xcd * TPX + tloc) * 256 + wv * 32;
        v4i acc[2][8];
        do_conv<2>(mw, xs, wlds, lane, quad, l15, acc);
        epi_p1<2>(acc, mw, quad, l15, binv, btt, xs_next);
    }
    if (local < 4) {
        int tile = xcd * TPX + 96 + (local >> 1);
        int mw = tile * 256 + (local & 1) * 128 + wv * 16;
        v4i acc[1][8];
        do_conv<1>(mw, xs, wlds, lane, quad, l15, acc);
        epi_p1<1>(acc, mw, quad, l15, binv, btt, xs_next);
    }
}

// ---------------------------------------------------------------------------
// Phase 2: persistent conv with the streaming block-staged epilogue.
__global__ __launch_bounds__(512, 1) void conv_p2(
    const int8_t* __restrict__ xs,
    const int8_t* __restrict__ wf,
    const float* __restrict__ bnp,
    const float* __restrict__ xres,
    float* __restrict__ out)
{
    __shared__ int8_t wlds[18 * 8192];       // 147,456 B
    __shared__ float  sm[8 * 256];           //   8,192 B  (total 155,648)
    int t = threadIdx.x, lane = t & 63, wv = t >> 6;
    int quad = lane >> 4, l15 = lane & 15;

    {
        const v4i* g = (const v4i*)wf;
        v4i* l = (v4i*)wlds;
        for (int i = t; i < 18 * 512; i += 512) l[i] = g[i];
    }
    float binv[8], btt[8];
    {
        int o0 = 256 + l15 * 8, o1 = 384 + l15 * 8;
#pragma unroll
        for (int n = 0; n < 8; ++n) { binv[n] = bnp[o0 + n]; btt[n] = bnp[o1 + n]; }
    }
    __syncthreads();

    int xcd = blockIdx.x & 7, local = blockIdx.x >> 3;
#pragma unroll 1
    for (int tloc = local; tloc < 96; tloc += 32) {
        int m0 = (xcd * TPX + tloc) * 256;
        int mw = m0 + wv * 32;
        v4i acc[2][8];
        do_conv<2>(mw, xs, wlds, lane, quad, l15, acc);
        epi_p2<2>(acc, m0, wv, quad, l15, binv, btt, xres, out, sm);
    }
    if (local < 4) {
        int tile = xcd * TPX + 96 + (local >> 1);
        int m0 = tile * 256 + (local & 1) * 128;
        int mw = m0 + wv * 16;
        v4i acc[1][8];
        do_conv<1>(mw, xs, wlds, lane, quad, l15, acc);
        epi_p2<1>(acc, m0, wv, quad, l15, binv, btt, xres, out, sm);
    }
}

// ---------------------------------------------------------------------------
extern "C" void kernel_launch(void* const* d_in, const int* in_sizes, int n_in,
                              void* d_out, int out_size, void* d_ws, size_t ws_size,
                              hipStream_t stream) {
    const float* x   = (const float*)d_in[0];
    const float* w1  = (const float*)d_in[1];
    const float* w2  = (const float*)d_in[2];
    const float* g1  = (const float*)d_in[3];
    const float* be1 = (const float*)d_in[4];
    const float* mu1 = (const float*)d_in[5];
    const float* va1 = (const float*)d_in[6];
    const float* g2  = (const float*)d_in[7];
    const float* be2 = (const float*)d_in[8];
    const float* mu2 = (const float*)d_in[9];
    const float* va2 = (const float*)d_in[10];

    int8_t* ws  = (int8_t*)d_ws;
    int8_t* xs1 = ws + XS1_OFF;
    int8_t* xs2 = ws + XS2_OFF;
    int8_t* wf1 = ws + WF1_OFF;
    int8_t* wf2 = ws + WF2_OFF;
    float*  bnp = (float*)(ws + BNP_OFF);

    zero_halo<<<256, 256, 0, stream>>>(xs1, xs2);
    prep_x<<<M / 256, 256, 0, stream>>>(x, xs1);
    prep_w<<<(2 * 18 * 8 * 64 + 255) / 256, 256, 0, stream>>>(
        w1, w2, g1, be1, mu1, va1, g2, be2, mu2, va2, wf1, wf2, bnp);

    conv_p1<<<256, 512, 0, stream>>>(xs1, wf1, bnp, xs2);
    conv_p2<<<256, 512, 0, stream>>>(xs2, wf2, bnp, x, (float*)d_out);
}

// Round 7
// 332.140 us; speedup vs baseline: 1.1067x; 1.1067x over previous
//
#include <hip/hip_runtime.h>
#include <cstdint>
#include <cstddef>

// Binarized basic block on MI355X.
// |acc| <= 9*128 = 1152 < THRESH=8000 -> the per-partial-sum clip never binds
// -> both convs are exact int convolutions of sign() values. int8 implicit
// GEMM via mfma_i32_16x16x64_i8; float ops bit-exact vs numpy fp32.
//
// R16: (a) REVERT R15's LDS-staged p2 epilogue (+53us regression; the
//  "BW-bound" claim was circular: hbm_gbps is derived from dur. 1.2-2.1 TB/s
//  is far below the 6.3 ceiling -> never BW-bound). Back to R12 direct
//  gather. (b) RETRY R14's tail-fold with the register cap fixed: R14's
//  VGPR_Count=128 (heuristic cap at 512-thr blocks) spilled the RG=3 path
//  (~200 regs needed) -> merged round ran at spill speed = as slow as the
//  4th round it replaced. amdgpu_waves_per_eu(2,2) forces the 2-wave/EU
//  target -> 256-VGPR budget -> RG3 fits. Work/capacity = 98/32 = 3.0625
//  rounds; static schedule was paying 4. Expected: conv ~100 -> ~78.
//  Tell: VGPR must read ~200-256. 128 => attribute failed.

typedef int      v4i __attribute__((ext_vector_type(4)));
typedef float    v4f __attribute__((ext_vector_type(4)));
typedef unsigned int v2u __attribute__((ext_vector_type(2)));

constexpr int B = 64, C = 128, H = 56, W = 56;
constexpr int HP = H + 2, WP = W + 2;      // zero-padded spatial
constexpr int PIX = H * W;                 // 3136
constexpr int M = B * H * W;               // 200704 = 784 * 256
constexpr int NTILES = M / 256;            // 784 tiles of 256 rows
constexpr int TPX = NTILES / 8;            // 98 tiles per XCD

// workspace layout (bytes)
constexpr size_t XS_BYTES = (size_t)B * HP * WP * C;   // 27,557,888
constexpr size_t XS1_OFF = 0;
constexpr size_t XS2_OFF = XS_BYTES;
constexpr size_t WF_BYTES = 18 * 8192;                 // 147,456
constexpr size_t WF1_OFF = 2 * XS_BYTES;
constexpr size_t WF2_OFF = WF1_OFF + WF_BYTES;
constexpr size_t BNP_OFF = WF2_OFF + WF_BYTES;         // 4*128 floats

// ---------------------------------------------------------------------------
// Zero only the padded halos of xs1/xs2. 256 blocks: 4 per image.
__global__ __launch_bounds__(256) void zero_halo(int8_t* __restrict__ xs1,
                                                 int8_t* __restrict__ xs2) {
    int b = blockIdx.x >> 2;
    int q = blockIdx.x & 3;
    int t = q * 256 + threadIdx.x;           // 0..1023
    size_t ib = (size_t)b * HP * WP * C;
#pragma unroll
    for (int a = 0; a < 2; ++a) {
        uint32_t* p = (uint32_t*)((a ? xs2 : xs1) + ib);
        const int ROWD = WP * C / 4;             // 1856 dwords per padded row
        for (int i = t; i < ROWD; i += 1024) {
            p[i] = 0;
            p[(HP - 1) * ROWD + i] = 0;
        }
        for (int i = t; i < 56 * 2 * 32; i += 1024) {
            int r = i >> 6;
            int side = (i >> 5) & 1;
            int j = i & 31;
            p[((r + 1) * WP + side * (WP - 1)) * (C / 4) + j] = 0;
        }
    }
}

// ---------------------------------------------------------------------------
// sign(x) -> padded NHWC int8 via LDS transpose (16 B/lane full-line stores).
__global__ __launch_bounds__(256) void prep_x(const float* __restrict__ x,
                                              int8_t* __restrict__ xs) {
    __shared__ uint32_t tl[256 * 33];
    int t = threadIdx.x;
    int m = blockIdx.x * 256 + t;
    int b_ = m / PIX, hw = m % PIX;
    const float* xp = x + (size_t)b_ * C * PIX + hw;
#pragma unroll
    for (int c4 = 0; c4 < 32; ++c4) {
        uint32_t v = 0;
#pragma unroll
        for (int j = 0; j < 4; ++j) {
            float f = __builtin_nontemporal_load(xp + (size_t)(c4 * 4 + j) * PIX);
            v |= ((uint32_t)(uint8_t)(int8_t)((f > 0.f) - (f < 0.f))) << (8 * j);
        }
        tl[t * 33 + c4] = v;
    }
    __syncthreads();
    int pl = t >> 3, co = t & 7;
#pragma unroll
    for (int pass = 0; pass < 8; ++pass) {
        int p = pass * 32 + pl;
        int mg = blockIdx.x * 256 + p;
        int b2 = mg / PIX, hw2 = mg % PIX, h2 = hw2 / W, w2 = hw2 % W;
        size_t ob = ((size_t)(b2 * HP + h2 + 1) * WP + (w2 + 1)) * C + co * 16;
        v4i val;
#pragma unroll
        for (int k = 0; k < 4; ++k) val[k] = (int)tl[p * 33 + co * 4 + k];
        *(v4i*)(xs + ob) = val;
    }
}

// ---------------------------------------------------------------------------
// Binarize weights into MFMA B-fragment order, slot = r*6 + kh*3 + s, with
// o = (lane&15)*8 + n (lane-contiguous O). BN tables exactly numpy fp32.
__global__ __launch_bounds__(256) void prep_w(
    const float* __restrict__ w1, const float* __restrict__ w2,
    const float* __restrict__ g1, const float* __restrict__ be1,
    const float* __restrict__ mu1, const float* __restrict__ va1,
    const float* __restrict__ g2, const float* __restrict__ be2,
    const float* __restrict__ mu2, const float* __restrict__ va2,
    int8_t* __restrict__ wf1, int8_t* __restrict__ wf2,
    float* __restrict__ bnp) {
    int t = blockIdx.x * 256 + threadIdx.x;
    if (t < 256) {
        int o = t & 127;
        if (t < 128) {
            float inv = g1[o] / sqrtf(va1[o] + 1e-5f);
            bnp[o]       = inv;
            bnp[128 + o] = __fsub_rn(be1[o], __fmul_rn(mu1[o], inv));
        } else {
            float inv = g2[o] / sqrtf(va2[o] + 1e-5f);
            bnp[256 + o] = inv;
            bnp[384 + o] = __fsub_rn(be2[o], __fmul_rn(mu2[o], inv));
        }
    }
    if (t >= 2 * 18 * 8 * 64) return;
    int lane = t & 63;
    int nsub = (t >> 6) & 7;
    int kh   = (t >> 9) & 1;
    int tap  = (t >> 10) % 9;
    int which = (t >> 10) / 9;
    const float* w = which ? w2 : w1;
    int8_t* wf = which ? wf2 : wf1;
    int o = (lane & 15) * 8 + nsub;
    int cbase = kh * 64 + (lane >> 4) * 16;
    int r = tap / 3, s = tap % 3;
    int slot = r * 6 + kh * 3 + s;           // (r, kh, s) step order
    int8_t frag[16];
#pragma unroll
    for (int j = 0; j < 16; ++j) {
        float f = w[((size_t)(o * C + cbase + j) * 3 + r) * 3 + s];
        frag[j] = (int8_t)((f > 0.f) - (f < 0.f));
    }
    *(v4i*)(wf + (size_t)((slot * 8 + nsub) * 64 + lane) * 16) =
        *(const v4i*)frag;
}

// ---------------------------------------------------------------------------
// K-loop (R12's pinned ping-pong): RG 16-row groups (arbitrary starts via
// mrows[]) x all 128 O. prefetch(s+1) pinned before MFMA(s) via
// sched_barrier(0); compiler emits counted waits for the old set only.
template <int RG>
__device__ __forceinline__ void do_conv(
    const int (&mrows)[RG], const int8_t* __restrict__ xs, const int8_t* wlds,
    int lane, int quad, int l15, v4i (&acc)[RG][8])
{
    int abase[RG];
#pragma unroll
    for (int rg = 0; rg < RG; ++rg) {
        int ma = mrows[rg] + l15;
        int wa = ma % W; int ta = ma / W; int ha = ta % H; int ba = ta / H;
        abase[rg] = ((ba * HP + ha) * WP + wa) * C + quad * 16;
    }
    int lidx = lane << 4;

#pragma unroll
    for (int rg = 0; rg < RG; ++rg)
#pragma unroll
        for (int n = 0; n < 8; ++n) acc[rg][n] = (v4i)0;

    v4i a0[RG], a1[RG], bf0[8], bf1[8];
#pragma unroll
    for (int rg = 0; rg < RG; ++rg) a0[rg] = *(const v4i*)(xs + abase[rg]);
#pragma unroll
    for (int n = 0; n < 8; ++n)
        bf0[n] = *(const v4i*)(wlds + n * 1024 + lidx);
    __builtin_amdgcn_sched_barrier(0);

    const int8_t* wl = wlds;
    int aoffr = 0;
#pragma unroll 1
    for (int r3 = 0; r3 < 3; ++r3) {
#pragma unroll
        for (int kk = 0; kk < 6; ++kk) {
            const bool last = (r3 == 2) && (kk == 5);
            if (!last) {
                const int nkh = (kk + 1 < 6) ? ((kk + 1) / 3) : 0;
                const int ns  = (kk + 1 < 6) ? ((kk + 1) % 3) : 0;
                const int rbump = (kk + 1 < 6) ? 0 : WP * C;
                int naoff = aoffr + rbump + nkh * 64 + ns * C;
                const int8_t* lb = wl + (kk + 1) * 8192;
                if (((kk + 1) & 1) == 0) {
#pragma unroll
                    for (int rg = 0; rg < RG; ++rg)
                        a0[rg] = *(const v4i*)(xs + abase[rg] + naoff);
#pragma unroll
                    for (int n = 0; n < 8; ++n)
                        bf0[n] = *(const v4i*)(lb + n * 1024 + lidx);
                } else {
#pragma unroll
                    for (int rg = 0; rg < RG; ++rg)
                        a1[rg] = *(const v4i*)(xs + abase[rg] + naoff);
#pragma unroll
                    for (int n = 0; n < 8; ++n)
                        bf1[n] = *(const v4i*)(lb + n * 1024 + lidx);
                }
            }
            __builtin_amdgcn_sched_barrier(0);
            __builtin_amdgcn_s_setprio(1);
            if ((kk & 1) == 0) {
#pragma unroll
                for (int n = 0; n < 8; ++n)
#pragma unroll
                    for (int rg = 0; rg < RG; ++rg)
                        acc[rg][n] = __builtin_amdgcn_mfma_i32_16x16x64_i8(
                            a0[rg], bf0[n], acc[rg][n], 0, 0, 0);
            } else {
#pragma unroll
                for (int n = 0; n < 8; ++n)
#pragma unroll
                    for (int rg = 0; rg < RG; ++rg)
                        acc[rg][n] = __builtin_amdgcn_mfma_i32_16x16x64_i8(
                            a1[rg], bf1[n], acc[rg][n], 0, 0, 0);
            }
            __builtin_amdgcn_s_setprio(0);
            __builtin_amdgcn_sched_barrier(0);
        }
        aoffr += WP * C;
        wl += 6 * 8192;
    }
}

// ---------------------------------------------------------------------------
// Phase-1 epilogue (per-wave): sign(bn(acc)) -> xs_next, full-line v2u
// stores (128-B contiguous per 16 lanes).
template <int RG>
__device__ __forceinline__ void epi_p1(
    v4i (&acc)[RG][8], const int (&mrows)[RG], int quad, int l15,
    const float* binv, const float* btt, int8_t* __restrict__ xs_next)
{
#pragma unroll
    for (int rg = 0; rg < RG; ++rg) {
        int m0 = mrows[rg] + quad * 4;
        int w0 = m0 % W; int t0 = m0 / W; int h0 = t0 % H; int b0 = t0 / H;
        int base = ((b0 * HP + h0 + 1) * WP + (w0 + 1)) * C + l15 * 8;
#pragma unroll
        for (int i = 0; i < 4; ++i) {
            uint32_t lo = 0, hi = 0;
#pragma unroll
            for (int n = 0; n < 8; ++n) {
                float y = __fadd_rn(__fmul_rn((float)acc[rg][n][i], binv[n]), btt[n]);
                uint32_t sb = (uint8_t)(int8_t)((y > 0.f) - (y < 0.f));
                if (n < 4) lo |= sb << (8 * n);
                else       hi |= sb << (8 * (n - 4));
            }
            v2u pk; pk[0] = lo; pk[1] = hi;
            *(v2u*)(xs_next + base + i * C) = pk;
        }
    }
}

// ---------------------------------------------------------------------------
// Phase-2 epilogue (per-wave direct gather, R12 style): bn + residual + clip.
template <int RG>
__device__ __forceinline__ void epi_p2(
    v4i (&acc)[RG][8], const int (&mrows)[RG], int quad, int l15,
    const float* binv, const float* btt,
    const float* __restrict__ xres, float* __restrict__ out)
{
#pragma unroll
    for (int rg = 0; rg < RG; ++rg) {
        int m0 = mrows[rg] + quad * 4;                // multiple of 4; W%4==0
        int w0 = m0 % W; int t0 = m0 / W; int h0 = t0 % H; int b0 = t0 / H;
        int pixb = b0 * C * PIX + h0 * W + w0;
#pragma unroll
        for (int n = 0; n < 8; ++n) {
            int idx = pixb + (l15 * 8 + n) * PIX;
            v4f r = __builtin_nontemporal_load((const v4f*)(xres + idx));
            v4f z;
#pragma unroll
            for (int i = 0; i < 4; ++i) {
                float y = __fadd_rn(__fmul_rn((float)acc[rg][n][i], binv[n]), btt[n]);
                float v = __fadd_rn(y, r[i]);
                z[i] = fminf(fmaxf(v, -1.f), 1.f);
            }
            __builtin_nontemporal_store(z, (v4f*)(out + idx));
        }
    }
}

// ---------------------------------------------------------------------------
// Phase 1: persistent conv. 256 blocks (1/CU), 512 thr = 8 waves (2/SIMD).
// EXACTLY 3 rounds: rounds 0-1 RG=2; round 2 blocks local<4 run RG=3 (their
// tile + one 16-row group of the 2 leftover tiles/XCD). waves_per_eu(2,2)
// lifts the VGPR heuristic cap to 256 so RG=3 (~220 regs) doesn't spill
// (R14's failure mode: cap 128 -> spill -> merged round at spill speed).
__global__ __attribute__((amdgpu_flat_work_group_size(512, 512)))
__attribute__((amdgpu_waves_per_eu(2, 2))) void conv_p1(
    const int8_t* __restrict__ xs,
    const int8_t* __restrict__ wf,
    const float* __restrict__ bnp,
    int8_t* __restrict__ xs_next)
{
    __shared__ int8_t wlds[18 * 8192];       // 147,456 B
    int t = threadIdx.x, lane = t & 63, wv = t >> 6;
    int quad = lane >> 4, l15 = lane & 15;

    {
        const v4i* g = (const v4i*)wf;
        v4i* l = (v4i*)wlds;
        for (int i = t; i < 18 * 512; i += 512) l[i] = g[i];
    }
    float binv[8], btt[8];
    {
        int o0 = l15 * 8, o1 = 128 + l15 * 8;
#pragma unroll
        for (int n = 0; n < 8; ++n) { binv[n] = bnp[o0 + n]; btt[n] = bnp[o1 + n]; }
    }
    __syncthreads();

    int xcd = blockIdx.x & 7, local = blockIdx.x >> 3;
#pragma unroll 1
    for (int rd = 0; rd < 2; ++rd) {
        int mw = (xcd * TPX + local + rd * 32) * 256 + wv * 32;
        int mrows2[2] = { mw, mw + 16 };
        v4i acc[2][8];
        do_conv<2>(mrows2, xs, wlds, lane, quad, l15, acc);
        epi_p1<2>(acc, mrows2, quad, l15, binv, btt, xs_next);
    }
    {
        int mw = (xcd * TPX + local + 64) * 256 + wv * 32;
        if (local < 4) {
            int tailrow = (xcd * TPX + 96) * 256 + (local * 8 + wv) * 16;
            int mrows3[3] = { mw, mw + 16, tailrow };
            v4i acc[3][8];
            do_conv<3>(mrows3, xs, wlds, lane, quad, l15, acc);
            epi_p1<3>(acc, mrows3, quad, l15, binv, btt, xs_next);
        } else {
            int mrows2[2] = { mw, mw + 16 };
            v4i acc[2][8];
            do_conv<2>(mrows2, xs, wlds, lane, quad, l15, acc);
            epi_p1<2>(acc, mrows2, quad, l15, binv, btt, xs_next);
        }
    }
}

// ---------------------------------------------------------------------------
// Phase 2: same schedule; epilogue = per-wave direct gather + residual.
__global__ __attribute__((amdgpu_flat_work_group_size(512, 512)))
__attribute__((amdgpu_waves_per_eu(2, 2))) void conv_p2(
    const int8_t* __restrict__ xs,
    const int8_t* __restrict__ wf,
    const float* __restrict__ bnp,
    const float* __restrict__ xres,
    float* __restrict__ out)
{
    __shared__ int8_t wlds[18 * 8192];       // 147,456 B
    int t = threadIdx.x, lane = t & 63, wv = t >> 6;
    int quad = lane >> 4, l15 = lane & 15;

    {
        const v4i* g = (const v4i*)wf;
        v4i* l = (v4i*)wlds;
        for (int i = t; i < 18 * 512; i += 512) l[i] = g[i];
    }
    float binv[8], btt[8];
    {
        int o0 = 256 + l15 * 8, o1 = 384 + l15 * 8;
#pragma unroll
        for (int n = 0; n < 8; ++n) { binv[n] = bnp[o0 + n]; btt[n] = bnp[o1 + n]; }
    }
    __syncthreads();

    int xcd = blockIdx.x & 7, local = blockIdx.x >> 3;
#pragma unroll 1
    for (int rd = 0; rd < 2; ++rd) {
        int mw = (xcd * TPX + local + rd * 32) * 256 + wv * 32;
        int mrows2[2] = { mw, mw + 16 };
        v4i acc[2][8];
        do_conv<2>(mrows2, xs, wlds, lane, quad, l15, acc);
        epi_p2<2>(acc, mrows2, quad, l15, binv, btt, xres, out);
    }
    {
        int mw = (xcd * TPX + local + 64) * 256 + wv * 32;
        if (local < 4) {
            int tailrow = (xcd * TPX + 96) * 256 + (local * 8 + wv) * 16;
            int mrows3[3] = { mw, mw + 16, tailrow };
            v4i acc[3][8];
            do_conv<3>(mrows3, xs, wlds, lane, quad, l15, acc);
            epi_p2<3>(acc, mrows3, quad, l15, binv, btt, xres, out);
        } else {
            int mrows2[2] = { mw, mw + 16 };
            v4i acc[2][8];
            do_conv<2>(mrows2, xs, wlds, lane, quad, l15, acc);
            epi_p2<2>(acc, mrows2, quad, l15, binv, btt, xres, out);
        }
    }
}

// ---------------------------------------------------------------------------
extern "C" void kernel_launch(void* const* d_in, const int* in_sizes, int n_in,
                              void* d_out, int out_size, void* d_ws, size_t ws_size,
                              hipStream_t stream) {
    const float* x   = (const float*)d_in[0];
    const float* w1  = (const float*)d_in[1];
    const float* w2  = (const float*)d_in[2];
    const float* g1  = (const float*)d_in[3];
    const float* be1 = (const float*)d_in[4];
    const float* mu1 = (const float*)d_in[5];
    const float* va1 = (const float*)d_in[6];
    const float* g2  = (const float*)d_in[7];
    const float* be2 = (const float*)d_in[8];
    const float* mu2 = (const float*)d_in[9];
    const float* va2 = (const float*)d_in[10];

    int8_t* ws  = (int8_t*)d_ws;
    int8_t* xs1 = ws + XS1_OFF;
    int8_t* xs2 = ws + XS2_OFF;
    int8_t* wf1 = ws + WF1_OFF;
    int8_t* wf2 = ws + WF2_OFF;
    float*  bnp = (float*)(ws + BNP_OFF);

    zero_halo<<<256, 256, 0, stream>>>(xs1, xs2);
    prep_x<<<M / 256, 256, 0, stream>>>(x, xs1);
    prep_w<<<(2 * 18 * 8 * 64 + 255) / 256, 256, 0, stream>>>(
        w1, w2, g1, be1, mu1, va1, g2, be2, mu2, va2, wf1, wf2, bnp);

    conv_p1<<<256, 512, 0, stream>>>(xs1, wf1, bnp, xs2);
    conv_p2<<<256, 512, 0, stream>>>(xs2, wf2, bnp, x, (float*)d_out);
}

// Round 8
// 323.807 us; speedup vs baseline: 1.1351x; 1.0257x over previous
//
#include <hip/hip_runtime.h>
#include <cstdint>
#include <cstddef>

// Binarized basic block on MI355X.
// |acc| <= 9*128 = 1152 < THRESH=8000 -> the per-partial-sum clip never binds
// -> both convs are exact int convolutions of sign() values. int8 implicit
// GEMM via mfma_i32_16x16x64_i8; float ops bit-exact vs numpy fp32.
//
// R17: HAND-CONTROLLED A-SIDE WAITS (asm loads + counted vmcnt, depth-2).
//  Ledger R10-R16: occupancy, prefetch depth (C++), pinning, wave shape,
//  tail schedule, epilogue granule ALL falsified; per-step wall ~3.4-4.5k cyc
//  invariant. Never controlled: the s_waitcnt themselves. If the compiler
//  emits a drain-class wait per step, every step pays full loaded A-latency
//  (L2 200-500, L3/HBM ~900+, loaded ~2-4k) -> the invariant wall.
//  -> A-loads via inline-asm global_load_dwordx4 (invisible to the compiler
//     waitcnt pass, HK pattern), 3-slot depth-2 pipeline (slot = kk%3,
//     compile-time), my waits only: vmcnt(2*RG) steady (2 newer A-sets stay
//     in flight, NEVER 0 mid-loop), vmcnt(0) last 2 steps + tile end (so the
//     epilogue's compiler-tracked waits stay correct). sched_barrier(0)
//     right after each wait (rule #18). B-side stays C++ (compiler lgkm
//     insertion is fine-grained per the m97 asm evidence).
//  Readout: win -> conv 100->55-75 each. Null -> vm side exonerated; next
//  round = visible ablation kernels. VGPR expected ~110-130.

typedef int      v4i __attribute__((ext_vector_type(4)));
typedef float    v4f __attribute__((ext_vector_type(4)));
typedef unsigned int v2u __attribute__((ext_vector_type(2)));

constexpr int B = 64, C = 128, H = 56, W = 56;
constexpr int HP = H + 2, WP = W + 2;      // zero-padded spatial
constexpr int PIX = H * W;                 // 3136
constexpr int M = B * H * W;               // 200704 = 784 * 256
constexpr int NTILES = M / 256;            // 784 tiles of 256 rows
constexpr int TPX = NTILES / 8;            // 98 tiles per XCD

// workspace layout (bytes)
constexpr size_t XS_BYTES = (size_t)B * HP * WP * C;   // 27,557,888
constexpr size_t XS1_OFF = 0;
constexpr size_t XS2_OFF = XS_BYTES;
constexpr size_t WF_BYTES = 18 * 8192;                 // 147,456
constexpr size_t WF1_OFF = 2 * XS_BYTES;
constexpr size_t WF2_OFF = WF1_OFF + WF_BYTES;
constexpr size_t BNP_OFF = WF2_OFF + WF_BYTES;         // 4*128 floats

// ---------------------------------------------------------------------------
// Zero only the padded halos of xs1/xs2. 256 blocks: 4 per image.
__global__ __launch_bounds__(256) void zero_halo(int8_t* __restrict__ xs1,
                                                 int8_t* __restrict__ xs2) {
    int b = blockIdx.x >> 2;
    int q = blockIdx.x & 3;
    int t = q * 256 + threadIdx.x;           // 0..1023
    size_t ib = (size_t)b * HP * WP * C;
#pragma unroll
    for (int a = 0; a < 2; ++a) {
        uint32_t* p = (uint32_t*)((a ? xs2 : xs1) + ib);
        const int ROWD = WP * C / 4;             // 1856 dwords per padded row
        for (int i = t; i < ROWD; i += 1024) {
            p[i] = 0;
            p[(HP - 1) * ROWD + i] = 0;
        }
        for (int i = t; i < 56 * 2 * 32; i += 1024) {
            int r = i >> 6;
            int side = (i >> 5) & 1;
            int j = i & 31;
            p[((r + 1) * WP + side * (WP - 1)) * (C / 4) + j] = 0;
        }
    }
}

// ---------------------------------------------------------------------------
// sign(x) -> padded NHWC int8 via LDS transpose (16 B/lane full-line stores).
__global__ __launch_bounds__(256) void prep_x(const float* __restrict__ x,
                                              int8_t* __restrict__ xs) {
    __shared__ uint32_t tl[256 * 33];
    int t = threadIdx.x;
    int m = blockIdx.x * 256 + t;
    int b_ = m / PIX, hw = m % PIX;
    const float* xp = x + (size_t)b_ * C * PIX + hw;
#pragma unroll
    for (int c4 = 0; c4 < 32; ++c4) {
        uint32_t v = 0;
#pragma unroll
        for (int j = 0; j < 4; ++j) {
            float f = __builtin_nontemporal_load(xp + (size_t)(c4 * 4 + j) * PIX);
            v |= ((uint32_t)(uint8_t)(int8_t)((f > 0.f) - (f < 0.f))) << (8 * j);
        }
        tl[t * 33 + c4] = v;
    }
    __syncthreads();
    int pl = t >> 3, co = t & 7;
#pragma unroll
    for (int pass = 0; pass < 8; ++pass) {
        int p = pass * 32 + pl;
        int mg = blockIdx.x * 256 + p;
        int b2 = mg / PIX, hw2 = mg % PIX, h2 = hw2 / W, w2 = hw2 % W;
        size_t ob = ((size_t)(b2 * HP + h2 + 1) * WP + (w2 + 1)) * C + co * 16;
        v4i val;
#pragma unroll
        for (int k = 0; k < 4; ++k) val[k] = (int)tl[p * 33 + co * 4 + k];
        *(v4i*)(xs + ob) = val;
    }
}

// ---------------------------------------------------------------------------
// Binarize weights into MFMA B-fragment order, slot = r*6 + kh*3 + s, with
// o = (lane&15)*8 + n (lane-contiguous O). BN tables exactly numpy fp32.
__global__ __launch_bounds__(256) void prep_w(
    const float* __restrict__ w1, const float* __restrict__ w2,
    const float* __restrict__ g1, const float* __restrict__ be1,
    const float* __restrict__ mu1, const float* __restrict__ va1,
    const float* __restrict__ g2, const float* __restrict__ be2,
    const float* __restrict__ mu2, const float* __restrict__ va2,
    int8_t* __restrict__ wf1, int8_t* __restrict__ wf2,
    float* __restrict__ bnp) {
    int t = blockIdx.x * 256 + threadIdx.x;
    if (t < 256) {
        int o = t & 127;
        if (t < 128) {
            float inv = g1[o] / sqrtf(va1[o] + 1e-5f);
            bnp[o]       = inv;
            bnp[128 + o] = __fsub_rn(be1[o], __fmul_rn(mu1[o], inv));
        } else {
            float inv = g2[o] / sqrtf(va2[o] + 1e-5f);
            bnp[256 + o] = inv;
            bnp[384 + o] = __fsub_rn(be2[o], __fmul_rn(mu2[o], inv));
        }
    }
    if (t >= 2 * 18 * 8 * 64) return;
    int lane = t & 63;
    int nsub = (t >> 6) & 7;
    int kh   = (t >> 9) & 1;
    int tap  = (t >> 10) % 9;
    int which = (t >> 10) / 9;
    const float* w = which ? w2 : w1;
    int8_t* wf = which ? wf2 : wf1;
    int o = (lane & 15) * 8 + nsub;
    int cbase = kh * 64 + (lane >> 4) * 16;
    int r = tap / 3, s = tap % 3;
    int slot = r * 6 + kh * 3 + s;           // (r, kh, s) step order
    int8_t frag[16];
#pragma unroll
    for (int j = 0; j < 16; ++j) {
        float f = w[((size_t)(o * C + cbase + j) * 3 + r) * 3 + s];
        frag[j] = (int8_t)((f > 0.f) - (f < 0.f));
    }
    *(v4i*)(wf + (size_t)((slot * 8 + nsub) * 64 + lane) * 16) =
        *(const v4i*)frag;
}

// ---------------------------------------------------------------------------
// Counted A-wait helpers (literal immediates; if constexpr dispatch).
template <int N>
__device__ __forceinline__ void wait_vm() {
    if constexpr (N == 0) asm volatile("s_waitcnt vmcnt(0)");
    else if constexpr (N == 2) asm volatile("s_waitcnt vmcnt(2)");
    else if constexpr (N == 4) asm volatile("s_waitcnt vmcnt(4)");
    else if constexpr (N == 6) asm volatile("s_waitcnt vmcnt(6)");
}

// ---------------------------------------------------------------------------
// K-loop: RG 16-row groups x 128 O. A-side = inline-asm global_load_dwordx4,
// 3-slot depth-2 pipeline (slot = kk%3 compile-time; 6 substeps = 0 mod 3),
// counted waits vmcnt(2*RG) steady / vmcnt(0) last 2 steps. B-side = C++
// LDS ping-pong (set = kk&1), compiler-managed lgkm waits.
template <int RG>
__device__ __forceinline__ void do_conv(
    const int (&mrows)[RG], const int8_t* __restrict__ xs, const int8_t* wlds,
    int lane, int quad, int l15, v4i (&acc)[RG][8])
{
    const int8_t* ap[RG];
#pragma unroll
    for (int rg = 0; rg < RG; ++rg) {
        int ma = mrows[rg] + l15;
        int wa = ma % W; int ta = ma / W; int ha = ta % H; int ba = ta / H;
        ap[rg] = xs + ((ba * HP + ha) * WP + wa) * C + quad * 16;
    }
    int lidx = lane << 4;

#pragma unroll
    for (int rg = 0; rg < RG; ++rg)
#pragma unroll
        for (int n = 0; n < 8; ++n) acc[rg][n] = (v4i)0;

    v4i a[3][RG];        // A slots; slot(st) = kk%3 (compile-time)
    v4i bf0[8], bf1[8];  // B ping-pong; set = kk&1

    // prologue: A(0)->slot0 (off 0), A(1)->slot1 (off C); B(0)->set0.
#pragma unroll
    for (int rg = 0; rg < RG; ++rg)
        asm volatile("global_load_dwordx4 %0, %1, off"
                     : "=v"(a[0][rg]) : "v"(ap[rg]));
#pragma unroll
    for (int rg = 0; rg < RG; ++rg)
        asm volatile("global_load_dwordx4 %0, %1, off"
                     : "=v"(a[1][rg]) : "v"(ap[rg] + C));
#pragma unroll
    for (int n = 0; n < 8; ++n)
        bf0[n] = *(const v4i*)(wlds + n * 1024 + lidx);
    __builtin_amdgcn_sched_barrier(0);

    const int8_t* wl = wlds;                 // LDS base for this r
    int aoffr = 0;                           // r * WP * C
#pragma unroll 1
    for (int r3 = 0; r3 < 3; ++r3) {
#pragma unroll
        for (int kk = 0; kk < 6; ++kk) {
            // ---- A prefetch: step st+2 -> slot (kk+2)%3 (skip if st+2>17)
            if (kk <= 3 || r3 != 2) {
                const int kp = (kk + 2) % 6;           // target substep
                const int rb = (kk <= 3) ? 0 : WP * C; // crosses r-boundary
                const int noff = rb + (kp / 3) * 64 + (kp % 3) * C;
#pragma unroll
                for (int rg = 0; rg < RG; ++rg) {
                    const int8_t* p = ap[rg] + aoffr + noff;
                    asm volatile("global_load_dwordx4 %0, %1, off"
                                 : "=v"(a[(kk + 2) % 3][rg]) : "v"(p));
                }
            }
            // ---- B prefetch: step st+1 -> set (kk+1)&1 (skip if st+1>17)
            if (kk < 5 || r3 != 2) {
                const int8_t* lb = wl + (kk + 1) * 8192;  // kk=5 -> next r
                if (((kk + 1) & 1) == 0) {
#pragma unroll
                    for (int n = 0; n < 8; ++n)
                        bf0[n] = *(const v4i*)(lb + n * 1024 + lidx);
                } else {
#pragma unroll
                    for (int n = 0; n < 8; ++n)
                        bf1[n] = *(const v4i*)(lb + n * 1024 + lidx);
                }
            }
            __builtin_amdgcn_sched_barrier(0);
            // ---- A wait: allow the 2 newer A sets; drain at the very end.
            if (r3 == 2 && kk >= 4) wait_vm<0>();
            else                    wait_vm<2 * RG>();
            __builtin_amdgcn_sched_barrier(0);
            __builtin_amdgcn_s_setprio(1);
            if ((kk & 1) == 0) {
#pragma unroll
                for (int n = 0; n < 8; ++n)
#pragma unroll
                    for (int rg = 0; rg < RG; ++rg)
                        acc[rg][n] = __builtin_amdgcn_mfma_i32_16x16x64_i8(
                            a[kk % 3][rg], bf0[n], acc[rg][n], 0, 0, 0);
            } else {
#pragma unroll
                for (int n = 0; n < 8; ++n)
#pragma unroll
                    for (int rg = 0; rg < RG; ++rg)
                        acc[rg][n] = __builtin_amdgcn_mfma_i32_16x16x64_i8(
                            a[kk % 3][rg], bf1[n], acc[rg][n], 0, 0, 0);
            }
            __builtin_amdgcn_s_setprio(0);
            __builtin_amdgcn_sched_barrier(0);
        }
        aoffr += WP * C;
        wl += 6 * 8192;
    }
}

// ---------------------------------------------------------------------------
// Phase-1 epilogue (per-wave): sign(bn(acc)) -> xs_next, full-line v2u
// stores (128-B contiguous per 16 lanes).
template <int RG>
__device__ __forceinline__ void epi_p1(
    v4i (&acc)[RG][8], const int (&mrows)[RG], int quad, int l15,
    const float* binv, const float* btt, int8_t* __restrict__ xs_next)
{
#pragma unroll
    for (int rg = 0; rg < RG; ++rg) {
        int m0 = mrows[rg] + quad * 4;
        int w0 = m0 % W; int t0 = m0 / W; int h0 = t0 % H; int b0 = t0 / H;
        int base = ((b0 * HP + h0 + 1) * WP + (w0 + 1)) * C + l15 * 8;
#pragma unroll
        for (int i = 0; i < 4; ++i) {
            uint32_t lo = 0, hi = 0;
#pragma unroll
            for (int n = 0; n < 8; ++n) {
                float y = __fadd_rn(__fmul_rn((float)acc[rg][n][i], binv[n]), btt[n]);
                uint32_t sb = (uint8_t)(int8_t)((y > 0.f) - (y < 0.f));
                if (n < 4) lo |= sb << (8 * n);
                else       hi |= sb << (8 * (n - 4));
            }
            v2u pk; pk[0] = lo; pk[1] = hi;
            *(v2u*)(xs_next + base + i * C) = pk;
        }
    }
}

// ---------------------------------------------------------------------------
// Phase-2 epilogue (per-wave direct gather): bn + residual + clip.
template <int RG>
__device__ __forceinline__ void epi_p2(
    v4i (&acc)[RG][8], const int (&mrows)[RG], int quad, int l15,
    const float* binv, const float* btt,
    const float* __restrict__ xres, float* __restrict__ out)
{
#pragma unroll
    for (int rg = 0; rg < RG; ++rg) {
        int m0 = mrows[rg] + quad * 4;                // multiple of 4; W%4==0
        int w0 = m0 % W; int t0 = m0 / W; int h0 = t0 % H; int b0 = t0 / H;
        int pixb = b0 * C * PIX + h0 * W + w0;
#pragma unroll
        for (int n = 0; n < 8; ++n) {
            int idx = pixb + (l15 * 8 + n) * PIX;
            v4f r = __builtin_nontemporal_load((const v4f*)(xres + idx));
            v4f z;
#pragma unroll
            for (int i = 0; i < 4; ++i) {
                float y = __fadd_rn(__fmul_rn((float)acc[rg][n][i], binv[n]), btt[n]);
                float v = __fadd_rn(y, r[i]);
                z[i] = fminf(fmaxf(v, -1.f), 1.f);
            }
            __builtin_nontemporal_store(z, (v4f*)(out + idx));
        }
    }
}

// ---------------------------------------------------------------------------
// Phase 1: persistent conv. 256 blocks (1/CU), 512 thr = 8 waves (2/SIMD).
// R12 schedule: 3 rounds RG=2 + tail round (local<4, RG=1 half-tiles).
__global__ __launch_bounds__(512, 1) void conv_p1(
    const int8_t* __restrict__ xs,
    const int8_t* __restrict__ wf,
    const float* __restrict__ bnp,
    int8_t* __restrict__ xs_next)
{
    __shared__ int8_t wlds[18 * 8192];       // 147,456 B
    int t = threadIdx.x, lane = t & 63, wv = t >> 6;
    int quad = lane >> 4, l15 = lane & 15;

    {
        const v4i* g = (const v4i*)wf;
        v4i* l = (v4i*)wlds;
        for (int i = t; i < 18 * 512; i += 512) l[i] = g[i];
    }
    float binv[8], btt[8];
    {
        int o0 = l15 * 8, o1 = 128 + l15 * 8;
#pragma unroll
        for (int n = 0; n < 8; ++n) { binv[n] = bnp[o0 + n]; btt[n] = bnp[o1 + n]; }
    }
    __syncthreads();

    int xcd = blockIdx.x & 7, local = blockIdx.x >> 3;
#pragma unroll 1
    for (int tloc = local; tloc < 96; tloc += 32) {
        int mw = (xcd * TPX + tloc) * 256 + wv * 32;
        int mrows2[2] = { mw, mw + 16 };
        v4i acc[2][8];
        do_conv<2>(mrows2, xs, wlds, lane, quad, l15, acc);
        epi_p1<2>(acc, mrows2, quad, l15, binv, btt, xs_next);
    }
    if (local < 4) {
        int tile = xcd * TPX + 96 + (local >> 1);
        int mw = tile * 256 + (local & 1) * 128 + wv * 16;
        int mrows1[1] = { mw };
        v4i acc[1][8];
        do_conv<1>(mrows1, xs, wlds, lane, quad, l15, acc);
        epi_p1<1>(acc, mrows1, quad, l15, binv, btt, xs_next);
    }
}

// ---------------------------------------------------------------------------
// Phase 2: same schedule; epilogue = per-wave direct gather + residual.
__global__ __launch_bounds__(512, 1) void conv_p2(
    const int8_t* __restrict__ xs,
    const int8_t* __restrict__ wf,
    const float* __restrict__ bnp,
    const float* __restrict__ xres,
    float* __restrict__ out)
{
    __shared__ int8_t wlds[18 * 8192];       // 147,456 B
    int t = threadIdx.x, lane = t & 63, wv = t >> 6;
    int quad = lane >> 4, l15 = lane & 15;

    {
        const v4i* g = (const v4i*)wf;
        v4i* l = (v4i*)wlds;
        for (int i = t; i < 18 * 512; i += 512) l[i] = g[i];
    }
    float binv[8], btt[8];
    {
        int o0 = 256 + l15 * 8, o1 = 384 + l15 * 8;
#pragma unroll
        for (int n = 0; n < 8; ++n) { binv[n] = bnp[o0 + n]; btt[n] = bnp[o1 + n]; }
    }
    __syncthreads();

    int xcd = blockIdx.x & 7, local = blockIdx.x >> 3;
#pragma unroll 1
    for (int tloc = local; tloc < 96; tloc += 32) {
        int mw = (xcd * TPX + tloc) * 256 + wv * 32;
        int mrows2[2] = { mw, mw + 16 };
        v4i acc[2][8];
        do_conv<2>(mrows2, xs, wlds, lane, quad, l15, acc);
        epi_p2<2>(acc, mrows2, quad, l15, binv, btt, xres, out);
    }
    if (local < 4) {
        int tile = xcd * TPX + 96 + (local >> 1);
        int mw = tile * 256 + (local & 1) * 128 + wv * 16;
        int mrows1[1] = { mw };
        v4i acc[1][8];
        do_conv<1>(mrows1, xs, wlds, lane, quad, l15, acc);
        epi_p2<1>(acc, mrows1, quad, l15, binv, btt, xres, out);
    }
}

// ---------------------------------------------------------------------------
extern "C" void kernel_launch(void* const* d_in, const int* in_sizes, int n_in,
                              void* d_out, int out_size, void* d_ws, size_t ws_size,
                              hipStream_t stream) {
    const float* x   = (const float*)d_in[0];
    const float* w1  = (const float*)d_in[1];
    const float* w2  = (const float*)d_in[2];
    const float* g1  = (const float*)d_in[3];
    const float* be1 = (const float*)d_in[4];
    const float* mu1 = (const float*)d_in[5];
    const float* va1 = (const float*)d_in[6];
    const float* g2  = (const float*)d_in[7];
    const float* be2 = (const float*)d_in[8];
    const float* mu2 = (const float*)d_in[9];
    const float* va2 = (const float*)d_in[10];

    int8_t* ws  = (int8_t*)d_ws;
    int8_t* xs1 = ws + XS1_OFF;
    int8_t* xs2 = ws + XS2_OFF;
    int8_t* wf1 = ws + WF1_OFF;
    int8_t* wf2 = ws + WF2_OFF;
    float*  bnp = (float*)(ws + BNP_OFF);

    zero_halo<<<256, 256, 0, stream>>>(xs1, xs2);
    prep_x<<<M / 256, 256, 0, stream>>>(x, xs1);
    prep_w<<<(2 * 18 * 8 * 64 + 255) / 256, 256, 0, stream>>>(
        w1, w2, g1, be1, mu1, va1, g2, be2, mu2, va2, wf1, wf2, bnp);

    conv_p1<<<256, 512, 0, stream>>>(xs1, wf1, bnp, xs2);
    conv_p2<<<256, 512, 0, stream>>>(xs2, wf2, bnp, x, (float*)d_out);
}